// Round 7
// baseline (510.532 us; speedup 1.0000x reference)
//
#include <hip/hip_runtime.h>
#include <hip/hip_bf16.h>
#include <cstdint>
#include <cstddef>

#define B_ 4
#define S_ 2048
#define E_ 768
#define H_ 12
#define D_ 64

typedef __bf16 bf16x8 __attribute__((ext_vector_type(8)));
typedef float f32x4 __attribute__((ext_vector_type(4)));

__constant__ float c_slopes[12] = {
    0.6299605249f, 0.396850263f, 0.25f, 0.1574901312f,
    0.0992125657f, 0.0625f, 0.0393725328f, 0.0248031414f,
    0.015625f, 0.0098431332f, 0.0062007854f, 0.00390625f};

__device__ __forceinline__ unsigned short f2bf_u(float f) {
    unsigned u = __builtin_bit_cast(unsigned, f);
    u += 0x7fffu + ((u >> 16) & 1u);   // round-to-nearest-even
    return (unsigned short)(u >> 16);
}
__device__ __forceinline__ __bf16 f2bf(float f) {
    unsigned short s = f2bf_u(f);
    return __builtin_bit_cast(__bf16, s);
}

// async global->LDS, 16B per lane, dest = wave-uniform base + lane*16
__device__ __forceinline__ void gload_lds16(const void* g, void* l) {
    __builtin_amdgcn_global_load_lds(
        (const __attribute__((address_space(1))) unsigned int*)g,
        (__attribute__((address_space(3))) unsigned int*)l, 16, 0, 0);
}

// ---------------------------------------------------------------------------
// prep: x fp32 -> bf16 (6.29M elems)
// ---------------------------------------------------------------------------
__global__ __launch_bounds__(256) void cvt_x(const float* __restrict__ src,
                                             __bf16* __restrict__ dst) {
    int i = (blockIdx.x * 256 + threadIdx.x) * 4;
    float4 v = *(const float4*)(src + i);
    ushort4 o;
    o.x = f2bf_u(v.x); o.y = f2bf_u(v.y); o.z = f2bf_u(v.z); o.w = f2bf_u(v.w);
    *(ushort4*)((unsigned short*)dst + i) = o;
}

// ---------------------------------------------------------------------------
// prep: W fp32 [k][n] -> Wt bf16 [n][k]; z picks which of 4 matrices
// ---------------------------------------------------------------------------
__global__ __launch_bounds__(256) void wtrans(const float* __restrict__ W0,
                                              const float* __restrict__ W1,
                                              const float* __restrict__ W2,
                                              const float* __restrict__ W3,
                                              __bf16* __restrict__ Wt) {
    const float* W = blockIdx.z == 0 ? W0 : blockIdx.z == 1 ? W1
                   : blockIdx.z == 2 ? W2 : W3;
    __bf16* out = Wt + (size_t)blockIdx.z * E_ * E_;
    __shared__ alignas(16) __bf16 ts[64 * 72];
    const int t = threadIdx.x;
    const int k0 = blockIdx.y * 64, n0 = blockIdx.x * 64;
#pragma unroll
    for (int i = 0; i < 4; i++) {
        int idx = i * 256 + t;          // 1024 float4 chunks
        int row = idx >> 4, c4 = idx & 15;
        float4 v = *(const float4*)(W + (size_t)(k0 + row) * E_ + n0 + c4 * 4);
        ts[(c4 * 4 + 0) * 72 + row] = f2bf(v.x);
        ts[(c4 * 4 + 1) * 72 + row] = f2bf(v.y);
        ts[(c4 * 4 + 2) * 72 + row] = f2bf(v.z);
        ts[(c4 * 4 + 3) * 72 + row] = f2bf(v.w);
    }
    __syncthreads();
#pragma unroll
    for (int i = 0; i < 2; i++) {
        int idx = i * 256 + t;          // 512 chunks of 8 bf16
        int r = idx >> 3, c8 = idx & 7;
        *(uint4*)((unsigned short*)out + (size_t)(n0 + r) * E_ + k0 + c8 * 8) =
            *(const uint4*)((const unsigned short*)ts + r * 72 + c8 * 8);
    }
}

// ---------------------------------------------------------------------------
// prep: V [bh][s][d] bf16 -> Vt [bh][d][s] bf16
// ---------------------------------------------------------------------------
__global__ __launch_bounds__(256) void vtrans(const __bf16* __restrict__ V,
                                              __bf16* __restrict__ Vt) {
    __shared__ alignas(16) __bf16 ts[64 * 72];
    const int t = threadIdx.x;
    const int s0 = blockIdx.x * 64;
    const size_t base = (size_t)blockIdx.y * S_ * D_;
#pragma unroll
    for (int i = 0; i < 2; i++) {
        int idx = i * 256 + t;          // 512 chunks of 8
        int row = idx >> 3, c8 = idx & 7;
        uint4 v = *(const uint4*)((const unsigned short*)V + base +
                                  (size_t)(s0 + row) * D_ + c8 * 8);
        const unsigned short* q = (const unsigned short*)&v;
#pragma unroll
        for (int j = 0; j < 8; j++)
            ts[(c8 * 8 + j) * 72 + row] = __builtin_bit_cast(__bf16, q[j]);
    }
    __syncthreads();
#pragma unroll
    for (int i = 0; i < 2; i++) {
        int idx = i * 256 + t;
        int d = idx >> 3, c8 = idx & 7;
        *(uint4*)((unsigned short*)Vt + base + (size_t)d * S_ + s0 + c8 * 8) =
            *(const uint4*)((const unsigned short*)ts + d * 72 + c8 * 8);
    }
}

// ---------------------------------------------------------------------------
// GEMM: out = A(8192x768 bf16) @ Wt^T + bias. Wt is [n][k] bf16.
// m97-style staging: global_load_lds width=16, unpadded 64B LDS rows.
// ---------------------------------------------------------------------------
template <bool PERM>
__global__ __launch_bounds__(256) void gemm_bf(
    const __bf16* __restrict__ A, const __bf16* __restrict__ WtAll,
    const float* __restrict__ b0, const float* __restrict__ b1,
    const float* __restrict__ b2,
    float* __restrict__ outF, __bf16* __restrict__ outB_base) {
    constexpr int Kd = E_, N = E_;
    __shared__ alignas(16) __bf16 Asm[128 * 32];   // 64B rows, no pad (m97)
    __shared__ alignas(16) __bf16 Bsm[128 * 32];

    const int t = threadIdx.x;
    const int w = t >> 6, lane = t & 63;
    const int qm = lane & 15, quad = lane >> 4;
    const int m0 = blockIdx.y * 128, n0 = blockIdx.x * 128;
    const int wm = (w >> 1) * 64, wn = (w & 1) * 64;
    const int z = blockIdx.z;
    const __bf16* Wt = WtAll + (size_t)z * Kd * N;
    const float* bias = PERM ? (z == 0 ? b0 : z == 1 ? b1 : b2) : b0;
    __bf16* outB = PERM ? outB_base + (size_t)z * ((size_t)B_ * S_ * E_) : nullptr;

    // staging: 1024B wave-chunk = 16 rows x 64B; wave w owns chunks {2w,2w+1}
    const int crow = lane >> 2;       // row within chunk
    const int ccol = lane & 3;        // 16B quarter within row

    f32x4 acc[4][4] = {};

    for (int k0 = 0; k0 < Kd; k0 += 32) {
#pragma unroll
        for (int cc = 0; cc < 2; cc++) {
            int chunk = w * 2 + cc;
            int row = chunk * 16 + crow;
            gload_lds16((const unsigned short*)A + (size_t)(m0 + row) * Kd + k0 + ccol * 8,
                        Asm + chunk * 512);
            gload_lds16((const unsigned short*)Wt + (size_t)(n0 + row) * Kd + k0 + ccol * 8,
                        Bsm + chunk * 512);
        }
        __syncthreads();

        bf16x8 af[4], bg[4];
#pragma unroll
        for (int i = 0; i < 4; i++)
            af[i] = *(const bf16x8*)(Asm + (wm + i * 16 + qm) * 32 + quad * 8);
#pragma unroll
        for (int j = 0; j < 4; j++)
            bg[j] = *(const bf16x8*)(Bsm + (wn + j * 16 + qm) * 32 + quad * 8);
#pragma unroll
        for (int i = 0; i < 4; i++)
#pragma unroll
            for (int j = 0; j < 4; j++)
                acc[i][j] = __builtin_amdgcn_mfma_f32_16x16x32_bf16(
                    af[i], bg[j], acc[i][j], 0, 0, 0);
        __syncthreads();
    }

    // epilogue: C/D layout col=lane&15, row=quad*4+reg
#pragma unroll
    for (int i = 0; i < 4; i++) {
#pragma unroll
        for (int j = 0; j < 4; j++) {
            int col = n0 + wn + j * 16 + qm;
            float bvv = bias[col];
#pragma unroll
            for (int r = 0; r < 4; r++) {
                int row = m0 + wm + i * 16 + quad * 4 + r;
                float val = acc[i][j][r] + bvv;
                if (PERM) {
                    int b = row >> 11, s = row & (S_ - 1);
                    int h = col >> 6, d = col & (D_ - 1);
                    outB[(((size_t)(b * H_ + h)) * S_ + s) * D_ + d] = f2bf(val);
                } else {
                    outF[(size_t)row * N + col] = val;
                }
            }
        }
    }
}

// ---------------------------------------------------------------------------
// Flash attention — BARRIER-FREE. Both MFMA operands load straight from
// global (D=64 makes A-frag rows of K and B-frag rows of Vt contiguous);
// only wave-private Psm remains in LDS, so there is no __syncthreads at
// all and every wave is an independent stream. S^T formulation +
// analytic-max softmax (exponent qk*scale*log2e - c2*key, q-independent).
// ---------------------------------------------------------------------------
__global__ __launch_bounds__(256, 6) void attn_k(
    const __bf16* __restrict__ Q, const __bf16* __restrict__ K,
    const __bf16* __restrict__ Vt, __bf16* __restrict__ O) {
    __shared__ alignas(16) __bf16 Psm[4 * 16 * 72];  // per-wave P [q][key]

    const int t = threadIdx.x;
    const int w = t >> 6, lane = t & 63;
    const int qm = lane & 15, quad = lane >> 4;
    const int qt = 31 - (int)blockIdx.x;          // longest first
    const int bh = blockIdx.y;
    const float c2 = c_slopes[bh % H_] * 1.44269504f;     // slope * log2(e)
    const size_t base = (size_t)bh * S_ * D_;
    const int bb = qt * 64 + w * 16;

    // Q B-fragments (lane qm = q-col, contiguous over d)
    const __bf16* qp = Q + base + (size_t)(bb + qm) * D_ + quad * 8;
    bf16x8 qf0 = *(const bf16x8*)qp;
    bf16x8 qf1 = *(const bf16x8*)(qp + 32);

    f32x4 oacc[4] = {};
    float lsum = 0.f;
    __bf16* Pw = Psm + w * 16 * 72;

    // global fragment base pointers
    const __bf16* Kp = K + base + (size_t)qm * D_ + quad * 8;   // + (kt*64+16i)*D
    const __bf16* Vp = Vt + base + (size_t)qm * S_ + quad * 8;  // + 16jd*S + kt*64
    const float kb0 = -c2 * (float)(4 * quad);

    for (int kt = 0; kt <= qt; kt++) {
        // S^T = K Q^T : A-frags straight from global K
        f32x4 st[4];
#pragma unroll
        for (int i = 0; i < 4; i++) {
            const __bf16* kp = Kp + (size_t)(kt * 64 + 16 * i) * D_;
            bf16x8 a0 = *(const bf16x8*)kp;
            bf16x8 a1 = *(const bf16x8*)(kp + 32);
            f32x4 zz = {0.f, 0.f, 0.f, 0.f};
            zz = __builtin_amdgcn_mfma_f32_16x16x32_bf16(a0, qf0, zz, 0, 0, 0);
            zz = __builtin_amdgcn_mfma_f32_16x16x32_bf16(a1, qf1, zz, 0, 0, 0);
            st[i] = zz;
        }

        // analytic-max softmax: p = exp2(qk*scale*log2e - c2*key)
        const int qi = bb + qm;
        const bool nomask = (kt * 64 + 63) <= bb;
        const float ktb = kb0 - c2 * (float)(kt * 64);
        float ls = 0.f;
        unsigned pk[4][2];
#pragma unroll
        for (int i = 0; i < 4; i++) {
            float p[4];
#pragma unroll
            for (int r = 0; r < 4; r++) {
                float tt = st[i][r] * 0.18033688f + (ktb - c2 * (float)(16 * i + r));
                float pp = __builtin_amdgcn_exp2f(tt);
                if (!nomask) {
                    int key = kt * 64 + 16 * i + 4 * quad + r;
                    pp = (key > qi) ? 0.f : pp;
                }
                ls += pp;
                p[r] = pp;
            }
            unsigned u0 = __builtin_bit_cast(unsigned, p[0]) + 0x8000u;
            unsigned u1 = __builtin_bit_cast(unsigned, p[1]) + 0x8000u;
            unsigned u2 = __builtin_bit_cast(unsigned, p[2]) + 0x8000u;
            unsigned u3 = __builtin_bit_cast(unsigned, p[3]) + 0x8000u;
            pk[i][0] = __builtin_amdgcn_perm(u1, u0, 0x07060302u);
            pk[i][1] = __builtin_amdgcn_perm(u3, u2, 0x07060302u);
        }
        lsum += ls;

        // P[q=qm][key=16i+4quad+{0..3}] : 4x ds_write_b64 (wave-private)
#pragma unroll
        for (int i = 0; i < 4; i++) {
            uint2 pv; pv.x = pk[i][0]; pv.y = pk[i][1];
            *(uint2*)((unsigned short*)Pw + qm * 72 + 16 * i + 4 * quad) = pv;
        }

        // O += P V : A = P rows (b128 from LDS), B-frags straight from Vt
        bf16x8 ap0 = *(const bf16x8*)(Pw + qm * 72 + quad * 8);
        bf16x8 ap1 = *(const bf16x8*)(Pw + qm * 72 + 32 + quad * 8);
#pragma unroll
        for (int jd = 0; jd < 4; jd++) {
            const __bf16* vp = Vp + (size_t)(16 * jd) * S_ + kt * 64;
            bf16x8 b0 = *(const bf16x8*)vp;
            bf16x8 b1 = *(const bf16x8*)(vp + 32);
            oacc[jd] = __builtin_amdgcn_mfma_f32_16x16x32_bf16(
                ap0, b0, oacc[jd], 0, 0, 0);
            oacc[jd] = __builtin_amdgcn_mfma_f32_16x16x32_bf16(
                ap1, b1, oacc[jd], 0, 0, 0);
        }
    }

    // epilogue: reduce l across quads (lane-local rows), divide, store
    float lf = lsum;
    lf += __shfl_xor(lf, 16);
    lf += __shfl_xor(lf, 32);               // full l for q = bb+qm
#pragma unroll
    for (int r = 0; r < 4; r++) {
        float lr = __shfl(lf, 4 * quad + r);  // l for q = bb+4quad+r
        float inv = 1.0f / lr;
        int qrow = bb + 4 * quad + r;
#pragma unroll
        for (int jd = 0; jd < 4; jd++)
            O[base + (size_t)qrow * D_ + 16 * jd + qm] =
                f2bf(oacc[jd][r] * inv);
    }
}

// ---------------------------------------------------------------------------
extern "C" void kernel_launch(void* const* d_in, const int* in_sizes, int n_in,
                              void* d_out, int out_size, void* d_ws, size_t ws_size,
                              hipStream_t stream) {
    (void)in_sizes; (void)n_in; (void)out_size; (void)ws_size;
    const float* x  = (const float*)d_in[0];
    const float* Wq = (const float*)d_in[1];
    const float* bq = (const float*)d_in[2];
    const float* Wk = (const float*)d_in[3];
    const float* bk = (const float*)d_in[4];
    const float* Wv = (const float*)d_in[5];
    const float* bv = (const float*)d_in[6];
    const float* Wo = (const float*)d_in[7];
    const float* bo = (const float*)d_in[8];
    float* out = (float*)d_out;

    const size_t n = (size_t)B_ * H_ * S_ * D_;  // 6291456
    // ws layout (55.0 MB total):
    //  [0,n):   xb (dead after QKV gemm) -> Vt (written by vtrans)
    //  [n,2n):  Qb -> Ob (attn reads only its own Q rows before writing them)
    //  [2n,3n): Kb
    //  [3n,4n): Vb natural (dead after vtrans)
    //  [4n,+):  Wt, 4 x 768*768 bf16
    __bf16* xb  = (__bf16*)d_ws;
    __bf16* Qb  = xb + n;
    __bf16* Kb  = xb + 2 * n;
    __bf16* Vb  = xb + 3 * n;
    __bf16* Wt  = xb + 4 * n;
    __bf16* Vtb = xb;
    __bf16* Ob  = Qb;

    cvt_x<<<6144, 256, 0, stream>>>(x, xb);
    wtrans<<<dim3(12, 12, 4), 256, 0, stream>>>(Wq, Wk, Wv, Wo, Wt);
    gemm_bf<true><<<dim3(6, 64, 3), 256, 0, stream>>>(
        xb, Wt, bq, bk, bv, nullptr, Qb);
    vtrans<<<dim3(32, 48), 256, 0, stream>>>(Vb, Vtb);
    attn_k<<<dim3(32, 48), 256, 0, stream>>>(Qb, Kb, Vtb, Ob);
    gemm_bf<false><<<dim3(6, 64, 1), 256, 0, stream>>>(
        Ob, Wt + 3 * (size_t)E_ * E_, bo, nullptr, nullptr, out, nullptr);
}

// Round 8
// 276.429 us; speedup vs baseline: 1.8469x; 1.8469x over previous
//
#include <hip/hip_runtime.h>
#include <hip/hip_bf16.h>
#include <cstdint>
#include <cstddef>

#define B_ 4
#define S_ 2048
#define E_ 768
#define H_ 12
#define D_ 64

typedef __bf16 bf16x8 __attribute__((ext_vector_type(8)));
typedef float f32x4 __attribute__((ext_vector_type(4)));

__constant__ float c_slopes[12] = {
    0.6299605249f, 0.396850263f, 0.25f, 0.1574901312f,
    0.0992125657f, 0.0625f, 0.0393725328f, 0.0248031414f,
    0.015625f, 0.0098431332f, 0.0062007854f, 0.00390625f};

__device__ __forceinline__ unsigned short f2bf_u(float f) {
    unsigned u = __builtin_bit_cast(unsigned, f);
    u += 0x7fffu + ((u >> 16) & 1u);   // round-to-nearest-even
    return (unsigned short)(u >> 16);
}
__device__ __forceinline__ __bf16 f2bf(float f) {
    unsigned short s = f2bf_u(f);
    return __builtin_bit_cast(__bf16, s);
}

// async global->LDS, 16B per lane, dest = wave-uniform base + lane*16
__device__ __forceinline__ void gload_lds16(const void* g, void* l) {
    __builtin_amdgcn_global_load_lds(
        (const __attribute__((address_space(1))) unsigned int*)g,
        (__attribute__((address_space(3))) unsigned int*)l, 16, 0, 0);
}

// ---------------------------------------------------------------------------
// prep: x fp32 -> bf16 (6.29M elems)
// ---------------------------------------------------------------------------
__global__ __launch_bounds__(256) void cvt_x(const float* __restrict__ src,
                                             __bf16* __restrict__ dst) {
    int i = (blockIdx.x * 256 + threadIdx.x) * 4;
    float4 v = *(const float4*)(src + i);
    ushort4 o;
    o.x = f2bf_u(v.x); o.y = f2bf_u(v.y); o.z = f2bf_u(v.z); o.w = f2bf_u(v.w);
    *(ushort4*)((unsigned short*)dst + i) = o;
}

// ---------------------------------------------------------------------------
// prep: W fp32 [k][n] -> Wt bf16 [n][k]; z picks which of 4 matrices
// ---------------------------------------------------------------------------
__global__ __launch_bounds__(256) void wtrans(const float* __restrict__ W0,
                                              const float* __restrict__ W1,
                                              const float* __restrict__ W2,
                                              const float* __restrict__ W3,
                                              __bf16* __restrict__ Wt) {
    const float* W = blockIdx.z == 0 ? W0 : blockIdx.z == 1 ? W1
                   : blockIdx.z == 2 ? W2 : W3;
    __bf16* out = Wt + (size_t)blockIdx.z * E_ * E_;
    __shared__ alignas(16) __bf16 ts[64 * 72];
    const int t = threadIdx.x;
    const int k0 = blockIdx.y * 64, n0 = blockIdx.x * 64;
#pragma unroll
    for (int i = 0; i < 4; i++) {
        int idx = i * 256 + t;          // 1024 float4 chunks
        int row = idx >> 4, c4 = idx & 15;
        float4 v = *(const float4*)(W + (size_t)(k0 + row) * E_ + n0 + c4 * 4);
        ts[(c4 * 4 + 0) * 72 + row] = f2bf(v.x);
        ts[(c4 * 4 + 1) * 72 + row] = f2bf(v.y);
        ts[(c4 * 4 + 2) * 72 + row] = f2bf(v.z);
        ts[(c4 * 4 + 3) * 72 + row] = f2bf(v.w);
    }
    __syncthreads();
#pragma unroll
    for (int i = 0; i < 2; i++) {
        int idx = i * 256 + t;          // 512 chunks of 8 bf16
        int r = idx >> 3, c8 = idx & 7;
        *(uint4*)((unsigned short*)out + (size_t)(n0 + r) * E_ + k0 + c8 * 8) =
            *(const uint4*)((const unsigned short*)ts + r * 72 + c8 * 8);
    }
}

// ---------------------------------------------------------------------------
// prep: V [bh][s][d] bf16 -> Vt [bh][d][s] bf16
// ---------------------------------------------------------------------------
__global__ __launch_bounds__(256) void vtrans(const __bf16* __restrict__ V,
                                              __bf16* __restrict__ Vt) {
    __shared__ alignas(16) __bf16 ts[64 * 72];
    const int t = threadIdx.x;
    const int s0 = blockIdx.x * 64;
    const size_t base = (size_t)blockIdx.y * S_ * D_;
#pragma unroll
    for (int i = 0; i < 2; i++) {
        int idx = i * 256 + t;          // 512 chunks of 8
        int row = idx >> 3, c8 = idx & 7;
        uint4 v = *(const uint4*)((const unsigned short*)V + base +
                                  (size_t)(s0 + row) * D_ + c8 * 8);
        const unsigned short* q = (const unsigned short*)&v;
#pragma unroll
        for (int j = 0; j < 8; j++)
            ts[(c8 * 8 + j) * 72 + row] = __builtin_bit_cast(__bf16, q[j]);
    }
    __syncthreads();
#pragma unroll
    for (int i = 0; i < 2; i++) {
        int idx = i * 256 + t;
        int d = idx >> 3, c8 = idx & 7;
        *(uint4*)((unsigned short*)Vt + base + (size_t)d * S_ + s0 + c8 * 8) =
            *(const uint4*)((const unsigned short*)ts + d * 72 + c8 * 8);
    }
}

// ---------------------------------------------------------------------------
// GEMM: out = A(8192x768 bf16) @ Wt^T + bias. Wt is [n][k] bf16.
// m97-style staging (global_load_lds width=16, 64B LDS rows) + BK=64 via
// twin BK=32 buffers: 32 MFMA per barrier pair instead of 16, same
// conflict-free 64B-row frag reads, LDS 32KB (VGPR still the occupancy
// limiter at ~3 blocks/CU).
// ---------------------------------------------------------------------------
template <bool PERM>
__global__ __launch_bounds__(256) void gemm_bf(
    const __bf16* __restrict__ A, const __bf16* __restrict__ WtAll,
    const float* __restrict__ b0, const float* __restrict__ b1,
    const float* __restrict__ b2,
    float* __restrict__ outF, __bf16* __restrict__ outB_base) {
    constexpr int Kd = E_, N = E_;
    __shared__ alignas(16) __bf16 Asm[2][128 * 32];   // 64B rows, no pad
    __shared__ alignas(16) __bf16 Bsm[2][128 * 32];

    const int t = threadIdx.x;
    const int w = t >> 6, lane = t & 63;
    const int qm = lane & 15, quad = lane >> 4;
    const int m0 = blockIdx.y * 128, n0 = blockIdx.x * 128;
    const int wm = (w >> 1) * 64, wn = (w & 1) * 64;
    const int z = blockIdx.z;
    const __bf16* Wt = WtAll + (size_t)z * Kd * N;
    const float* bias = PERM ? (z == 0 ? b0 : z == 1 ? b1 : b2) : b0;
    __bf16* outB = PERM ? outB_base + (size_t)z * ((size_t)B_ * S_ * E_) : nullptr;

    // staging: 1024B wave-chunk = 16 rows x 64B; wave w owns chunks {2w,2w+1}
    const int crow = lane >> 2;       // row within chunk
    const int ccol = lane & 3;        // 16B quarter within row

    f32x4 acc[4][4] = {};

    for (int k0 = 0; k0 < Kd; k0 += 64) {
#pragma unroll
        for (int h = 0; h < 2; h++) {
            int kh = k0 + h * 32;
#pragma unroll
            for (int cc = 0; cc < 2; cc++) {
                int chunk = w * 2 + cc;
                int row = chunk * 16 + crow;
                gload_lds16((const unsigned short*)A + (size_t)(m0 + row) * Kd + kh + ccol * 8,
                            Asm[h] + chunk * 512);
                gload_lds16((const unsigned short*)Wt + (size_t)(n0 + row) * Kd + kh + ccol * 8,
                            Bsm[h] + chunk * 512);
            }
        }
        __syncthreads();

#pragma unroll
        for (int h = 0; h < 2; h++) {
            bf16x8 af[4], bg[4];
#pragma unroll
            for (int i = 0; i < 4; i++)
                af[i] = *(const bf16x8*)(Asm[h] + (wm + i * 16 + qm) * 32 + quad * 8);
#pragma unroll
            for (int j = 0; j < 4; j++)
                bg[j] = *(const bf16x8*)(Bsm[h] + (wn + j * 16 + qm) * 32 + quad * 8);
#pragma unroll
            for (int i = 0; i < 4; i++)
#pragma unroll
                for (int j = 0; j < 4; j++)
                    acc[i][j] = __builtin_amdgcn_mfma_f32_16x16x32_bf16(
                        af[i], bg[j], acc[i][j], 0, 0, 0);
        }
        __syncthreads();
    }

    // epilogue: C/D layout col=lane&15, row=quad*4+reg
#pragma unroll
    for (int i = 0; i < 4; i++) {
#pragma unroll
        for (int j = 0; j < 4; j++) {
            int col = n0 + wn + j * 16 + qm;
            float bvv = bias[col];
#pragma unroll
            for (int r = 0; r < 4; r++) {
                int row = m0 + wm + i * 16 + quad * 4 + r;
                float val = acc[i][j][r] + bvv;
                if (PERM) {
                    int b = row >> 11, s = row & (S_ - 1);
                    int h = col >> 6, d = col & (D_ - 1);
                    outB[(((size_t)(b * H_ + h)) * S_ + s) * D_ + d] = f2bf(val);
                } else {
                    outF[(size_t)row * N + col] = val;
                }
            }
        }
    }
}

// ---------------------------------------------------------------------------
// Flash attention (S^T formulation, analytic-max softmax, causal + ALiBi).
// R6 kernel (known 102.9 us): ONE 64-q tile per block, LDS staging of K/Vt
// (R7 lesson: MFMA frags MUST come from LDS; global-direct frag loads put
// L2 latency inside every MFMA chain -> 3.4x regression). 5 blocks/CU.
// ---------------------------------------------------------------------------
__global__ __launch_bounds__(256, 5) void attn_k(
    const __bf16* __restrict__ Q, const __bf16* __restrict__ K,
    const __bf16* __restrict__ Vt, __bf16* __restrict__ O) {
    __shared__ alignas(16) __bf16 Ksm[64 * 72];   // [key][d]
    __shared__ alignas(16) __bf16 Vsm[64 * 72];   // [d][key]
    __shared__ alignas(16) __bf16 Psm[4 * 16 * 72];  // per-wave P [q][key]

    const int t = threadIdx.x;
    const int w = t >> 6, lane = t & 63;
    const int qm = lane & 15, quad = lane >> 4;
    const int qt = 31 - (int)blockIdx.x;          // longest first
    const int bh = blockIdx.y;
    const float c2 = c_slopes[bh % H_] * 1.44269504f;     // slope * log2(e)
    const size_t base = (size_t)bh * S_ * D_;

    // Q B-fragments (lane qm = q-col, contiguous over d)
    const int bb = qt * 64 + w * 16;
    const __bf16* qp = Q + base + (size_t)(bb + qm) * D_ + quad * 8;
    bf16x8 qf0 = *(const bf16x8*)qp;
    bf16x8 qf1 = *(const bf16x8*)(qp + 32);

    f32x4 oacc[4] = {};
    float lsum = 0.f;
    __bf16* Pw = Psm + w * 16 * 72;

    // staging addressing: 64 rows x 64 cols = 512 chunks of 8 bf16
    const int srow = t >> 3, sc = t & 7;

    for (int kt = 0; kt <= qt; kt++) {
        // stage K tile + Vt tile
#pragma unroll
        for (int i = 0; i < 2; i++) {
            *(uint4*)((unsigned short*)Ksm + (srow + i * 32) * 72 + sc * 8) =
                *(const uint4*)((const unsigned short*)K + base +
                                (size_t)(kt * 64 + srow + i * 32) * D_ + sc * 8);
            *(uint4*)((unsigned short*)Vsm + (srow + i * 32) * 72 + sc * 8) =
                *(const uint4*)((const unsigned short*)Vt + base +
                                (size_t)(srow + i * 32) * S_ + kt * 64 + sc * 8);
        }
        __syncthreads();

        // K A-frags (m=key) and V B-frags (n=d)
        bf16x8 ak[4][2], bv[4][2];
#pragma unroll
        for (int i = 0; i < 4; i++) {
            ak[i][0] = *(const bf16x8*)(Ksm + (16 * i + qm) * 72 + quad * 8);
            ak[i][1] = *(const bf16x8*)(Ksm + (16 * i + qm) * 72 + 32 + quad * 8);
        }
#pragma unroll
        for (int jd = 0; jd < 4; jd++) {
            bv[jd][0] = *(const bf16x8*)(Vsm + (16 * jd + qm) * 72 + quad * 8);
            bv[jd][1] = *(const bf16x8*)(Vsm + (16 * jd + qm) * 72 + 32 + quad * 8);
        }

        // S^T = K Q^T : lane (qm,quad) reg r holds S^T[key=16i+4quad+r][q=qm]
        f32x4 st[4];
#pragma unroll
        for (int i = 0; i < 4; i++) {
            f32x4 zz = {0.f, 0.f, 0.f, 0.f};
            zz = __builtin_amdgcn_mfma_f32_16x16x32_bf16(ak[i][0], qf0, zz, 0, 0, 0);
            zz = __builtin_amdgcn_mfma_f32_16x16x32_bf16(ak[i][1], qf1, zz, 0, 0, 0);
            st[i] = zz;
        }

        // analytic-max softmax: ALiBi max over keys is at k=0 (slope*(q-k)),
        // so subtracting slope*q gives exponent qk*scale*log2e - c2*key:
        // q-independent, bounded above by ~+4, no shuffles/running max.
        const int qi = bb + qm;
        const bool nomask = (kt * 64 + 63) <= bb;
        float ls = 0.f;
        unsigned pk[4][2];
#pragma unroll
        for (int i = 0; i < 4; i++) {
            float bi = -c2 * (float)(kt * 64 + 16 * i + 4 * quad);
            float p[4];
#pragma unroll
            for (int r = 0; r < 4; r++) {
                float tt = st[i][r] * 0.18033688f + (bi - c2 * (float)r);
                float pp = __builtin_amdgcn_exp2f(tt);
                if (!nomask) {
                    int key = kt * 64 + 16 * i + 4 * quad + r;
                    pp = (key > qi) ? 0.f : pp;
                }
                ls += pp;
                p[r] = pp;
            }
            // pack 4 fp32 -> 4 bf16 (round-half-up + v_perm byte select)
            unsigned u0 = __builtin_bit_cast(unsigned, p[0]) + 0x8000u;
            unsigned u1 = __builtin_bit_cast(unsigned, p[1]) + 0x8000u;
            unsigned u2 = __builtin_bit_cast(unsigned, p[2]) + 0x8000u;
            unsigned u3 = __builtin_bit_cast(unsigned, p[3]) + 0x8000u;
            pk[i][0] = __builtin_amdgcn_perm(u1, u0, 0x07060302u);
            pk[i][1] = __builtin_amdgcn_perm(u3, u2, 0x07060302u);
        }
        lsum += ls;

        // P[q=qm][key=16i+4quad+{0..3}] : 4x ds_write_b64
#pragma unroll
        for (int i = 0; i < 4; i++) {
            uint2 pv; pv.x = pk[i][0]; pv.y = pk[i][1];
            *(uint2*)((unsigned short*)Pw + qm * 72 + 16 * i + 4 * quad) = pv;
        }

        // O += P V : A = P rows (b128), B = V^T rows
        bf16x8 ap0 = *(const bf16x8*)(Pw + qm * 72 + quad * 8);
        bf16x8 ap1 = *(const bf16x8*)(Pw + qm * 72 + 32 + quad * 8);
#pragma unroll
        for (int jd = 0; jd < 4; jd++) {
            oacc[jd] = __builtin_amdgcn_mfma_f32_16x16x32_bf16(
                ap0, bv[jd][0], oacc[jd], 0, 0, 0);
            oacc[jd] = __builtin_amdgcn_mfma_f32_16x16x32_bf16(
                ap1, bv[jd][1], oacc[jd], 0, 0, 0);
        }
        __syncthreads();
    }

    // epilogue: reduce l across quads (lane-local rows), divide, store
    float lf = lsum;
    lf += __shfl_xor(lf, 16);
    lf += __shfl_xor(lf, 32);               // full l for q = bb+qm
#pragma unroll
    for (int r = 0; r < 4; r++) {
        float lr = __shfl(lf, 4 * quad + r);  // l for q = bb+4quad+r
        float inv = 1.0f / lr;
        int qrow = bb + 4 * quad + r;
#pragma unroll
        for (int jd = 0; jd < 4; jd++)
            O[base + (size_t)qrow * D_ + 16 * jd + qm] =
                f2bf(oacc[jd][r] * inv);
    }
}

// ---------------------------------------------------------------------------
extern "C" void kernel_launch(void* const* d_in, const int* in_sizes, int n_in,
                              void* d_out, int out_size, void* d_ws, size_t ws_size,
                              hipStream_t stream) {
    (void)in_sizes; (void)n_in; (void)out_size; (void)ws_size;
    const float* x  = (const float*)d_in[0];
    const float* Wq = (const float*)d_in[1];
    const float* bq = (const float*)d_in[2];
    const float* Wk = (const float*)d_in[3];
    const float* bk = (const float*)d_in[4];
    const float* Wv = (const float*)d_in[5];
    const float* bv = (const float*)d_in[6];
    const float* Wo = (const float*)d_in[7];
    const float* bo = (const float*)d_in[8];
    float* out = (float*)d_out;

    const size_t n = (size_t)B_ * H_ * S_ * D_;  // 6291456
    // ws layout (55.0 MB total):
    //  [0,n):   xb (dead after QKV gemm) -> Vt (written by vtrans)
    //  [n,2n):  Qb -> Ob (attn reads only its own Q rows before writing them)
    //  [2n,3n): Kb
    //  [3n,4n): Vb natural (dead after vtrans)
    //  [4n,+):  Wt, 4 x 768*768 bf16
    __bf16* xb  = (__bf16*)d_ws;
    __bf16* Qb  = xb + n;
    __bf16* Kb  = xb + 2 * n;
    __bf16* Vb  = xb + 3 * n;
    __bf16* Wt  = xb + 4 * n;
    __bf16* Vtb = xb;
    __bf16* Ob  = Qb;

    cvt_x<<<6144, 256, 0, stream>>>(x, xb);
    wtrans<<<dim3(12, 12, 4), 256, 0, stream>>>(Wq, Wk, Wv, Wo, Wt);
    gemm_bf<true><<<dim3(6, 64, 3), 256, 0, stream>>>(
        xb, Wt, bq, bk, bv, nullptr, Qb);
    vtrans<<<dim3(32, 48), 256, 0, stream>>>(Vb, Vtb);
    attn_k<<<dim3(32, 48), 256, 0, stream>>>(Qb, Kb, Vtb, Ob);
    gemm_bf<false><<<dim3(6, 64, 1), 256, 0, stream>>>(
        Ob, Wt + 3 * (size_t)E_ * E_, bo, nullptr, nullptr, out, nullptr);
}